// Round 2
// baseline (1126.744 us; speedup 1.0000x reference)
//
#include <hip/hip_runtime.h>

#define NUM_NODES 10000
#define NUM_EDGES 640000
#define D_FEAT 128

// ---------------------------------------------------------------------------
// Kernel 1: zero-init the output (harness poisons d_out with 0xAA each call).
// ---------------------------------------------------------------------------
__global__ void zero_out_kernel(float4* __restrict__ out, int n4) {
    int i = blockIdx.x * blockDim.x + threadIdx.x;
    if (i < n4) out[i] = make_float4(0.f, 0.f, 0.f, 0.f);
}

// ---------------------------------------------------------------------------
// Kernel 2: scatter-add. One thread per (edge, 4-feature chunk).
// 32 consecutive lanes handle one edge's 128 features -> coalesced float4
// gather from x[src], 4 scalar atomicAdds into out[dst].
// edge_index layout: [2, NUM_EDGES] row-major, delivered by harness as INT32
// (harness converts integer inputs to int32 regardless of reference int64).
// ---------------------------------------------------------------------------
__global__ __launch_bounds__(256) void scatter_add_kernel(
    const float4* __restrict__ x4,          // [NUM_NODES * 32] float4
    const int* __restrict__ ei,             // [2 * NUM_EDGES] int32
    float* __restrict__ out)                // [NUM_NODES * D_FEAT]
{
    unsigned idx = blockIdx.x * blockDim.x + threadIdx.x;
    unsigned e = idx >> 5;          // edge id
    unsigned c = idx & 31;          // float4 chunk within the 128-wide row
    if (e >= NUM_EDGES) return;

    int src = ei[e];
    int dst = ei[NUM_EDGES + e];

    float4 v = x4[(unsigned)src * 32u + c];
    float* o = out + (unsigned)dst * (unsigned)D_FEAT + c * 4u;
    atomicAdd(o + 0, v.x);
    atomicAdd(o + 1, v.y);
    atomicAdd(o + 2, v.z);
    atomicAdd(o + 3, v.w);
}

extern "C" void kernel_launch(void* const* d_in, const int* in_sizes, int n_in,
                              void* d_out, int out_size, void* d_ws, size_t ws_size,
                              hipStream_t stream) {
    const float* x   = (const float*)d_in[0];   // [10000, 128] f32
    const int*   ei  = (const int*)d_in[1];     // [2, 640000] int32 (see note)
    float*       out = (float*)d_out;           // [10000, 128] f32

    // Zero output (poisoned with 0xAA before every timed call).
    int n4 = (NUM_NODES * D_FEAT) / 4;          // 320000 float4
    zero_out_kernel<<<(n4 + 255) / 256, 256, 0, stream>>>((float4*)out, n4);

    // Scatter-add: NUM_EDGES * 32 threads.
    unsigned total = (unsigned)NUM_EDGES * 32u; // 20,480,000
    scatter_add_kernel<<<(total + 255) / 256, 256, 0, stream>>>(
        (const float4*)x, ei, out);
}

// Round 3
// 200.462 us; speedup vs baseline: 5.6207x; 5.6207x over previous
//
#include <hip/hip_runtime.h>

#define NUM_NODES 10000
#define NUM_EDGES 640000
#define D_FEAT 128

// ---------------------------------------------------------------------------
// Workspace layout (ints):
//   deg_off   [NUM_NODES+1]  -- edge counts per dst, then exclusive offsets
//   cursor    [NUM_NODES]    -- running fill cursor (copy of offsets)
//   src_sorted[NUM_EDGES]    -- src node ids grouped by dst
// Total: 660,001 ints = 2.64 MB of d_ws.
// ---------------------------------------------------------------------------

// K1: zero output (poisoned 0xAA) + zero histogram counts.
__global__ void zero_kernel(float4* __restrict__ out4, int n4,
                            int* __restrict__ counts, int ncnt) {
    int i = blockIdx.x * blockDim.x + threadIdx.x;
    if (i < n4) out4[i] = make_float4(0.f, 0.f, 0.f, 0.f);
    if (i < ncnt) counts[i] = 0;
}

// K2: histogram of dst.
__global__ __launch_bounds__(256) void hist_kernel(
    const int* __restrict__ ei, int* __restrict__ counts) {
    int e = blockIdx.x * blockDim.x + threadIdx.x;
    if (e < NUM_EDGES) atomicAdd(&counts[ei[NUM_EDGES + e]], 1);
}

// K3: single-block exclusive scan over NUM_NODES counts (in place in deg_off),
// also writes cursor copy and the final total at deg_off[NUM_NODES].
#define SCAN_THREADS 256
#define SCAN_PER_T   40   // 256*40 = 10240 >= 10000
__global__ __launch_bounds__(SCAN_THREADS) void scan_kernel(
    int* __restrict__ deg_off, int* __restrict__ cursor) {
    __shared__ int sums[SCAN_THREADS];
    int t = threadIdx.x;
    int lo = t * SCAN_PER_T;
    int hi = min(lo + SCAN_PER_T, NUM_NODES);

    // pass 1: per-thread total
    int tot = 0;
    for (int i = lo; i < hi; ++i) tot += deg_off[i];
    sums[t] = tot;
    __syncthreads();

    // Hillis-Steele inclusive scan in LDS
    for (int off = 1; off < SCAN_THREADS; off <<= 1) {
        int v = sums[t];
        int add = (t >= off) ? sums[t - off] : 0;
        __syncthreads();
        sums[t] = v + add;
        __syncthreads();
    }
    int base = sums[t] - tot;   // exclusive prefix for this thread's chunk

    // pass 2: rewrite own range as exclusive offsets + cursor copy
    int run = base;
    for (int i = lo; i < hi; ++i) {
        int c = deg_off[i];
        deg_off[i] = run;
        cursor[i]  = run;
        run += c;
    }
    if (t == SCAN_THREADS - 1) deg_off[NUM_NODES] = sums[SCAN_THREADS - 1];
}

// K4: scatter src ids into dst-grouped order.
__global__ __launch_bounds__(256) void fill_kernel(
    const int* __restrict__ ei, int* __restrict__ cursor,
    int* __restrict__ src_sorted) {
    int e = blockIdx.x * blockDim.x + threadIdx.x;
    if (e < NUM_EDGES) {
        int src = ei[e];
        int dst = ei[NUM_EDGES + e];
        int pos = atomicAdd(&cursor[dst], 1);
        src_sorted[pos] = src;
    }
}

// K5: per-node gather reduction. One wave (64 lanes) per node; lane l holds
// features [2l, 2l+1] as float2 -> each x-row read is one coalesced 512 B
// wave transaction. Unroll by 4 for load-level ILP (independent addresses).
#define GATHER_WAVES_PER_BLOCK 4
__global__ __launch_bounds__(64 * GATHER_WAVES_PER_BLOCK) void gather_kernel(
    const float2* __restrict__ x2,          // [NUM_NODES * 64]
    const int* __restrict__ deg_off,
    const int* __restrict__ src_sorted,
    float2* __restrict__ out2)              // [NUM_NODES * 64]
{
    int wave = threadIdx.x >> 6;
    int lane = threadIdx.x & 63;
    int node = blockIdx.x * GATHER_WAVES_PER_BLOCK + wave;
    if (node >= NUM_NODES) return;

    int beg = deg_off[node];
    int end = deg_off[node + 1];

    float2 acc = make_float2(0.f, 0.f);
    int j = beg;
    for (; j + 4 <= end; j += 4) {
        int s0 = src_sorted[j];
        int s1 = src_sorted[j + 1];
        int s2 = src_sorted[j + 2];
        int s3 = src_sorted[j + 3];
        float2 v0 = x2[(unsigned)s0 * 64u + lane];
        float2 v1 = x2[(unsigned)s1 * 64u + lane];
        float2 v2 = x2[(unsigned)s2 * 64u + lane];
        float2 v3 = x2[(unsigned)s3 * 64u + lane];
        acc.x += v0.x + v1.x + v2.x + v3.x;
        acc.y += v0.y + v1.y + v2.y + v3.y;
    }
    for (; j < end; ++j) {
        int s = src_sorted[j];
        float2 v = x2[(unsigned)s * 64u + lane];
        acc.x += v.x;
        acc.y += v.y;
    }
    out2[(unsigned)node * 64u + lane] = acc;
}

extern "C" void kernel_launch(void* const* d_in, const int* in_sizes, int n_in,
                              void* d_out, int out_size, void* d_ws, size_t ws_size,
                              hipStream_t stream) {
    const float* x   = (const float*)d_in[0];   // [10000, 128] f32
    const int*   ei  = (const int*)d_in[1];     // [2, 640000] int32
    float*       out = (float*)d_out;           // [10000, 128] f32

    int* deg_off    = (int*)d_ws;               // NUM_NODES+1
    int* cursor     = deg_off + NUM_NODES + 1;  // NUM_NODES
    int* src_sorted = cursor + NUM_NODES;       // NUM_EDGES

    // K1: zero out + counts
    int n4 = (NUM_NODES * D_FEAT) / 4;          // 320000
    zero_kernel<<<(n4 + 255) / 256, 256, 0, stream>>>(
        (float4*)out, n4, deg_off, NUM_NODES + 1);

    // K2: histogram
    hist_kernel<<<(NUM_EDGES + 255) / 256, 256, 0, stream>>>(ei, deg_off);

    // K3: scan (single block)
    scan_kernel<<<1, SCAN_THREADS, 0, stream>>>(deg_off, cursor);

    // K4: fill dst-grouped src list
    fill_kernel<<<(NUM_EDGES + 255) / 256, 256, 0, stream>>>(
        ei, cursor, src_sorted);

    // K5: gather-reduce per node
    int nblocks = (NUM_NODES + GATHER_WAVES_PER_BLOCK - 1) / GATHER_WAVES_PER_BLOCK;
    gather_kernel<<<nblocks, 64 * GATHER_WAVES_PER_BLOCK, 0, stream>>>(
        (const float2*)x, deg_off, src_sorted, (float2*)out);
}